// Round 9
// baseline (5370.940 us; speedup 1.0000x reference)
//
#include <hip/hip_runtime.h>
#include <math.h>

constexpr int B_ = 64, T_ = 512, H_ = 256;

// ---------------------------------------------------------------------------
// Generic tiled fp32 GEMM: C[m][n] = act( sum_k A[arow(m)][k]*W[n][k] + bias[n] )
// BM=BN=128, BK=32, 256 threads, 8x8 micro-tile. grid = mtiles*ntiles*dirs.
// CHUNKMAP: A row = (m>>7)*512 + tbase + (m&127); m-tile == batch. Tiles whose
// whole t-range is >= lens[batch] produce only masked-out gates -> skip.
// ---------------------------------------------------------------------------
template <bool CHUNKMAP, bool RELU>
__global__ __launch_bounds__(256) void gemm_kernel(
    const float* __restrict__ A, const float* __restrict__ Wt,
    const float* __restrict__ bias, float* __restrict__ C0,
    float* __restrict__ C1, const int* __restrict__ lens,
    int K, int N, int mtiles, int ntiles, int tb0, int tb1)
{
  __shared__ float As[32][132];
  __shared__ float Bs[32][132];
  int bxx = blockIdx.x;
  const int mt = bxx % mtiles; bxx /= mtiles;
  const int nt = bxx % ntiles; const int dir = bxx / ntiles;
  const int tbase = dir ? tb1 : tb0;
  if (CHUNKMAP) {  // dead-tile skip: all 128 timesteps of this batch masked
    if (lens[mt] <= tbase) return;
  }
  const float* Wd = Wt + (long)dir * 768 * K;
  const float* bd = bias + dir * 768;
  float* Cd = dir ? C1 : C0;
  const int tid = threadIdx.x;
  const int tx = tid & 15, ty = tid >> 4;

  float acc[8][8];
  #pragma unroll
  for (int i = 0; i < 8; ++i)
    #pragma unroll
    for (int j = 0; j < 8; ++j) acc[i][j] = 0.f;

  const int KB = (K + 31) >> 5;
  for (int kb = 0; kb < KB; ++kb) {
    __syncthreads();
    #pragma unroll
    for (int e = 0; e < 16; ++e) {
      const int i = e * 256 + tid;
      const int r = i >> 5, kk = i & 31;
      const int kg = kb * 32 + kk;
      const int m = mt * 128 + r;
      long ar;
      if (CHUNKMAP) ar = (long)(m >> 7) * 512 + tbase + (m & 127);
      else          ar = m;
      As[kk][r] = (kg < K) ? A[ar * K + kg] : 0.f;
      Bs[kk][r] = (kg < K) ? Wd[(long)(nt * 128 + r) * K + kg] : 0.f;
    }
    __syncthreads();
    #pragma unroll 4
    for (int kk = 0; kk < 32; ++kk) {
      float a[8], b[8];
      #pragma unroll
      for (int i = 0; i < 8; ++i) a[i] = As[kk][i * 16 + ty];
      #pragma unroll
      for (int j = 0; j < 8; ++j) b[j] = Bs[kk][j * 16 + tx];
      #pragma unroll
      for (int i = 0; i < 8; ++i)
        #pragma unroll
        for (int j = 0; j < 8; ++j) acc[i][j] = fmaf(a[i], b[j], acc[i][j]);
    }
  }
  #pragma unroll
  for (int j = 0; j < 8; ++j) {
    const int n = nt * 128 + j * 16 + tx;
    const float bv = bd[n];
    #pragma unroll
    for (int i = 0; i < 8; ++i) {
      const int m = mt * 128 + i * 16 + ty;
      float v = acc[i][j] + bv;
      if (RELU) v = fmaxf(v, 0.f);
      Cd[(long)m * N + n] = v;
    }
  }
}

// Pin a float4 in VGPRs/AGPRs: opaque modification -> no rematerialization.
#define KEEP4(v) asm volatile("" : "+v"(v.x), "+v"(v.y), "+v"(v.z), "+v"(v.w))

// --- L3-coherence-point memory ops (sc0 sc1): bypass L1 and per-XCD L2.
// Proven correct+fast in r7. (r8's sc0-only "fast path" was the corruption.)
__device__ __forceinline__ void st_sys_f1(float* p, float v) {
  asm volatile("global_store_dword %0, %1, off sc0 sc1" :: "v"(p), "v"(v) : "memory");
}
__device__ __forceinline__ void st_sys_i1(int* p, int v) {
  asm volatile("global_store_dword %0, %1, off sc0 sc1" :: "v"(p), "v"(v) : "memory");
}
__device__ __forceinline__ float4 ld_sys_f4(const float* p) {
  float4 d;
  asm volatile("global_load_dwordx4 %0, %1, off sc0 sc1" : "=v"(d) : "v"(p) : "memory");
  asm volatile("s_waitcnt vmcnt(0)" ::: "memory");
  return d;
}
__device__ __forceinline__ int4 ld_sys_i4(const int* p) {
  int4 d;
  asm volatile("global_load_dwordx4 %0, %1, off sc0 sc1" : "=v"(d) : "v"(p) : "memory");
  asm volatile("s_waitcnt vmcnt(0)" ::: "memory");
  return d;
}
__device__ __forceinline__ void wait_vm0() {
  asm volatile("s_waitcnt vmcnt(0)" ::: "memory");
}

// ---------------------------------------------------------------------------
// Persistent GRU recurrence. 256 WGs x 768 threads.
// WG = (sgid = dir*32+group [2 batches], slice [64 units]); 4 slices/group.
// Sync: seq[sgid*16+slice] = publishes done (init->1, after step s -> s+2).
// Publisher = wave 0 only: h sc1-stores -> vmcnt(0) -> seq sc1-store.
// Consumer tid0 polls one dwordx4 (all 4 slices). 3 barriers/step.
// ---------------------------------------------------------------------------
template <int LAYER>
__global__ __launch_bounds__(768, 3) void rec_kernel(
    const float* __restrict__ xgf, const float* __restrict__ xgb,
    const float* __restrict__ whh, const float* __restrict__ bhh,
    const int* __restrict__ lens, float* __restrict__ out,
    float* __restrict__ stbuf, int* __restrict__ seqL, int sbase)
{
  __shared__ float hcur[2 * 336];   // [b][k + (k>>4)*4]
  __shared__ float ghs[2 * 200];    // [b][row], b-stride 200

  const int tid = threadIdx.x;
  const int bx = blockIdx.x;
  const int sgid = bx & 63, slice = bx >> 6;       // slice: 64 units
  const int dir = sgid >> 5, group = sgid & 31;    // group: 2 batches

  const int lane = tid & 63;
  const int kh = tid & 15;          // k-slice
  const int rtile = tid >> 4;       // 0..47, rows rtile*4..+4

  // Weights: w[i*4+q] = Whh[dir][rg(i)][kh*16 + q*4 ..+4), 16 float4, pinned.
  float4 w[16];
  {
    #pragma unroll
    for (int i = 0; i < 4; ++i) {
      const int lr = rtile * 4 + i;
      const int gate = lr >> 6, ur = lr & 63;
      const int rg = gate * 256 + slice * 64 + ur;
      const float* wr = whh + ((long)dir * 768 + rg) * 256 + kh * 16;
      #pragma unroll
      for (int q = 0; q < 4; ++q) w[i * 4 + q] = ((const float4*)wr)[q];
    }
    #pragma unroll
    for (int iq = 0; iq < 16; ++iq) KEEP4(w[iq]);
  }

  // gate-thread setup (tid < 64): unit u, BOTH batches
  const int u = tid;                    // valid when tid<64
  const int jg = slice * 64 + (tid & 63);
  const int bg0 = group * 2, bg1 = bg0 + 1;
  float bhr = 0.f, bhz = 0.f, bhn = 0.f;
  int lenb0 = 1, lenb1 = 1;
  if (tid < 64) {
    bhr = bhh[dir * 768 + jg];
    bhz = bhh[dir * 768 + 256 + jg];
    bhn = bhh[dir * 768 + 512 + jg];
    lenb0 = max(1, lens[bg0]);
    lenb1 = max(1, lens[bg1]);
  }
  const float* xg_my = (dir == 0) ? xgf : xgb;
  int* myseq = &seqL[sgid * 16 + slice];

  if (sbase == 0) {  // chunk 0: zero state buf0, publish (seq=1)
    if (tid < 64) {
      st_sys_f1(&stbuf[((dir * 2 + 0) * B_ + bg0) * H_ + jg], 0.f);
      st_sys_f1(&stbuf[((dir * 2 + 0) * B_ + bg1) * H_ + jg], 0.f);
    }
    wait_vm0();
    if (tid == 0) st_sys_i1(myseq, 1);
  }

  for (int ti = 0; ti < 128; ++ti) {
    const int s = sbase + ti;
    const int t = dir ? (T_ - 1 - s) : s;
    const int tt = dir ? (127 - ti) : ti;

    // xg prefetch for both batches (h-independent, before the poll)
    float xrv0 = 0.f, xzv0 = 0.f, xnv0 = 0.f;
    float xrv1 = 0.f, xzv1 = 0.f, xnv1 = 0.f;
    if (tid < 64) {
      const float* xr0 = xg_my + ((long)bg0 * 128 + tt) * 768;
      const float* xr1 = xg_my + ((long)bg1 * 128 + tt) * 768;
      xrv0 = xr0[jg]; xzv0 = xr0[256 + jg]; xnv0 = xr0[512 + jg];
      xrv1 = xr1[jg]; xzv1 = xr1[256 + jg]; xnv1 = xr1[512 + jg];
    }

    if (tid == 0) {  // wait: all 4 slices published step s-1 (seq >= s+1)
      for (;;) {
        int4 v = ld_sys_i4(&seqL[sgid * 16]);
        if (v.x > s && v.y > s && v.z > s && v.w > s) break;
      }
    }
    __syncthreads();  // S1

    // h staging: 2 batches x 256 floats (tid < 128, one float4 each)
    if (tid < 128) {
      const int bl = tid >> 6, k4 = tid & 63;
      const int rb = s & 1;
      float4 v = ld_sys_f4(
          &stbuf[(((dir * 2 + rb) * B_) + bg0 + bl) * H_ + k4 * 4]);
      *(float4*)&hcur[bl * 336 + k4 * 4 + (k4 >> 2) * 4] = v;
    }
    __syncthreads();  // S2

    // E: 4 rows x 16 k x 2 batches; weights in registers
    {
      float a0[4], a1[4];
      const float* hb0 = &hcur[kh * 20];
      const float* hb1 = &hcur[336 + kh * 20];
      float4 h0[4], h1v[4];
      #pragma unroll
      for (int q = 0; q < 4; ++q) h0[q]  = *(const float4*)&hb0[q * 4];
      #pragma unroll
      for (int q = 0; q < 4; ++q) h1v[q] = *(const float4*)&hb1[q * 4];
      #pragma unroll
      for (int i = 0; i < 4; ++i) { a0[i] = 0.f; a1[i] = 0.f; }
      #pragma unroll
      for (int q = 0; q < 4; ++q)
        #pragma unroll
        for (int i = 0; i < 4; ++i) {
          const float4 wv = w[i * 4 + q];
          a0[i] = fmaf(wv.x, h0[q].x, a0[i]);
          a0[i] = fmaf(wv.y, h0[q].y, a0[i]);
          a0[i] = fmaf(wv.z, h0[q].z, a0[i]);
          a0[i] = fmaf(wv.w, h0[q].w, a0[i]);
          a1[i] = fmaf(wv.x, h1v[q].x, a1[i]);
          a1[i] = fmaf(wv.y, h1v[q].y, a1[i]);
          a1[i] = fmaf(wv.z, h1v[q].z, a1[i]);
          a1[i] = fmaf(wv.w, h1v[q].w, a1[i]);
        }
      #pragma unroll
      for (int off = 1; off <= 8; off <<= 1) {
        #pragma unroll
        for (int i = 0; i < 4; ++i) {
          a0[i] += __shfl_xor(a0[i], off);
          a1[i] += __shfl_xor(a1[i], off);
        }
      }
      const int j = lane & 15;
      if (j < 8) {
        const int wb = j >> 2, wi = j & 3;
        float s0 = wb ? a1[0] : a0[0];
        float s1 = wb ? a1[1] : a0[1];
        float s2 = wb ? a1[2] : a0[2];
        float s3 = wb ? a1[3] : a0[3];
        float t0 = (wi & 1) ? s1 : s0;
        float t1 = (wi & 1) ? s3 : s2;
        float v  = (wi & 2) ? t1 : t0;
        ghs[wb * 200 + rtile * 4 + wi] = v;
      }
    }
    __syncthreads();  // S3

    // gates + publish: wave 0 only (both batches per thread)
    if (tid < 64) {
      const float gr0 = ghs[u]       + bhr, gr1 = ghs[200 + u] + bhr;
      const float gz0 = ghs[64 + u]  + bhz, gz1 = ghs[264 + u] + bhz;
      const float gn0 = ghs[128 + u] + bhn, gn1 = ghs[328 + u] + bhn;
      const float r0 = 1.f / (1.f + expf(-(xrv0 + gr0)));
      const float z0 = 1.f / (1.f + expf(-(xzv0 + gz0)));
      const float n0 = tanhf(xnv0 + r0 * gn0);
      const float r1 = 1.f / (1.f + expf(-(xrv1 + gr1)));
      const float z1 = 1.f / (1.f + expf(-(xzv1 + gz1)));
      const float n1 = tanhf(xnv1 + r1 * gn1);
      const float hold0 = hcur[jg + (jg >> 4) * 4];
      const float hold1 = hcur[336 + jg + (jg >> 4) * 4];
      const float hv0 = (t < lenb0) ? ((1.f - z0) * n0 + z0 * hold0) : hold0;
      const float hv1 = (t < lenb1) ? ((1.f - z1) * n1 + z1 * hold1) : hold1;
      const int wb = (s + 1) & 1;
      st_sys_f1(&stbuf[((dir * 2 + wb) * B_ + bg0) * H_ + jg], hv0);
      st_sys_f1(&stbuf[((dir * 2 + wb) * B_ + bg1) * H_ + jg], hv1);
      if (LAYER == 0) {
        out[((long)bg0 * T_ + t) * 512 + dir * 256 + jg] = hv0;
        out[((long)bg1 * T_ + t) * 512 + dir * 256 + jg] = hv1;
      } else if (s == T_ - 1) {
        out[(dir * B_ + bg0) * H_ + jg] = hv0;
        out[(dir * B_ + bg1) * H_ + jg] = hv1;
      }
    }
    wait_vm0();       // wave 0: h stores at L3 before seq
    if (tid == 0) st_sys_i1(myseq, s + 2);
    // no trailing barrier: only wave 0 published; S1 of next iter orders rest
  }
}

// ---------------------------------------------------------------------------
// Final: LayerNorm(concat(hf,hb)) @ fc_w^T + fc_b -> out[64][100]
// ---------------------------------------------------------------------------
__global__ __launch_bounds__(128) void final_kernel(
    const float* __restrict__ hfhb, const float* __restrict__ lng,
    const float* __restrict__ lnb, const float* __restrict__ fcw,
    const float* __restrict__ fcb, float* __restrict__ out)
{
  const int b = blockIdx.x, tid = threadIdx.x;
  __shared__ float y[512];
  __shared__ float wsum[2], wsum2[2];
  float s = 0.f, s2 = 0.f;
  for (int i = tid; i < 512; i += 128) {
    float v = (i < 256) ? hfhb[b * 256 + i] : hfhb[(64 + b) * 256 + (i - 256)];
    y[i] = v; s += v; s2 += v * v;
  }
  for (int off = 32; off; off >>= 1) { s += __shfl_down(s, off); s2 += __shfl_down(s2, off); }
  const int wv = tid >> 6;
  if ((tid & 63) == 0) { wsum[wv] = s; wsum2[wv] = s2; }
  __syncthreads();
  const float S = wsum[0] + wsum[1], S2 = wsum2[0] + wsum2[1];
  const float mu = S / 512.f;
  const float var = S2 / 512.f - mu * mu;
  const float rs = rsqrtf(var + 1e-5f);
  for (int i = tid; i < 512; i += 128) y[i] = (y[i] - mu) * rs * lng[i] + lnb[i];
  __syncthreads();
  for (int c = tid; c < 100; c += 128) {
    float acc = fcb[c];
    const float* wr = &fcw[c * 512];
    #pragma unroll 4
    for (int k = 0; k < 512; ++k) acc = fmaf(y[k], wr[k], acc);
    out[b * 100 + c] = acc;
  }
}

// ---------------------------------------------------------------------------
extern "C" void kernel_launch(void* const* d_in, const int* in_sizes, int n_in,
                              void* d_out, int out_size, void* d_ws, size_t ws_size,
                              hipStream_t stream)
{
  (void)in_sizes; (void)n_in; (void)out_size; (void)ws_size;
  const float* x    = (const float*)d_in[0];
  const float* pw   = (const float*)d_in[1];
  const float* pb   = (const float*)d_in[2];
  const float* wih0 = (const float*)d_in[3];
  const float* whh0 = (const float*)d_in[4];
  const float* bih0 = (const float*)d_in[5];
  const float* bhh0 = (const float*)d_in[6];
  const float* wih1 = (const float*)d_in[7];
  const float* whh1 = (const float*)d_in[8];
  const float* bih1 = (const float*)d_in[9];
  const float* bhh1 = (const float*)d_in[10];
  const float* lng  = (const float*)d_in[11];
  const float* lnb  = (const float*)d_in[12];
  const float* fcw  = (const float*)d_in[13];
  const float* fcb  = (const float*)d_in[14];
  const int*   lens = (const int*)d_in[15];
  float* out = (float*)d_out;

  char* ws = (char*)d_ws;
  int*   sync  = (int*)ws;                       // 16 KB: seq L0 [0,1024), seq L1 [1024,2048)
  float* hproj = (float*)(ws + 16384);           // 32768x128   (16.78 MB)
  float* h1    = (float*)(ws + 16793600);        // 32768x512   (67.11 MB)
  float* xgf   = (float*)(ws + 83902464);        // 64x128x768  (25.17 MB)
  float* xgb   = (float*)(ws + 109068288);       // 64x128x768  (25.17 MB)
  float* stbuf = (float*)(ws + 134234112);       // 2x2x64x256  (0.52 MB)
  float* hfhb  = (float*)(ws + 134758400);       // 2x64x256    (0.13 MB)

  hipMemsetAsync(sync, 0, 16384, stream);

  // proj: relu(x @ pw^T + pb) -> hproj  (M=32768, N=128, K=258)
  gemm_kernel<false, true><<<dim3(256), dim3(256), 0, stream>>>(
      x, pw, pb, hproj, hproj, nullptr, 258, 128, 256, 1, 0, 0);

  // Layer 0: per phase p, xg for fwd chunk p and bwd chunk 3-p, then 128 steps
  for (int p = 0; p < 4; ++p) {
    gemm_kernel<true, false><<<dim3(768), dim3(256), 0, stream>>>(
        hproj, wih0, bih0, xgf, xgb, lens, 128, 768, 64, 6, p * 128, (3 - p) * 128);
    rec_kernel<0><<<dim3(256), dim3(768), 0, stream>>>(
        xgf, xgb, whh0, bhh0, lens, h1, stbuf, sync, p * 128);
  }
  // Layer 1
  for (int p = 0; p < 4; ++p) {
    gemm_kernel<true, false><<<dim3(768), dim3(256), 0, stream>>>(
        h1, wih1, bih1, xgf, xgb, lens, 512, 768, 64, 6, p * 128, (3 - p) * 128);
    rec_kernel<1><<<dim3(256), dim3(768), 0, stream>>>(
        xgf, xgb, whh1, bhh1, lens, hfhb, stbuf, sync + 1024, p * 128);
  }

  final_kernel<<<dim3(64), dim3(128), 0, stream>>>(hfhb, lng, lnb, fcw, fcb, out);
}